// Round 1
// baseline (2549.045 us; speedup 1.0000x reference)
//
#include <hip/hip_runtime.h>
#include <math.h>

#define B_SZ 1024
#define T_SZ 512
#define C_CH 65
#define HID 160
#define G3  480   // 3*HID
#define OUTD 32

// ---------------- phase 0: zero any-flags ----------------
__global__ void k_zero(unsigned* __restrict__ anyv) {
  int i = blockIdx.x * blockDim.x + threadIdx.x;
  if (i < T_SZ) anyv[i] = 0u;
}

// ---------------- phase 1: obs[b][t] + any_obs[t] ----------------
__global__ __launch_bounds__(256) void k_obs(const float* __restrict__ X,
                                             unsigned char* __restrict__ obs,
                                             unsigned* __restrict__ anyv) {
  const int b = blockIdx.x;
  const float* Xb = X + (size_t)b * T_SZ * C_CH;
  for (int t = threadIdx.x; t < T_SZ; t += blockDim.x) {
    const float* cur = Xb + t * C_CH;
    const float* prv = cur - C_CH;
    float m = -1e30f;
    if (t == 0) {
      #pragma unroll
      for (int c = 1; c <= 32; ++c) m = fmaxf(m, cur[c]);
    } else {
      #pragma unroll
      for (int c = 1; c <= 32; ++c) m = fmaxf(m, cur[c] - prv[c]);
    }
    unsigned char o = (m > 0.5f) ? (unsigned char)1 : (unsigned char)0;
    obs[(size_t)b * T_SZ + t] = o;
    if (o) atomicOr(&anyv[t], 1u);
  }
}

__device__ __forceinline__ float sigm_f(float v) {
  return 1.f / (1.f + __expf(-v));
}
__device__ __forceinline__ float tanh_f(float v) {
  float a = fabsf(v);
  float e = __expf(-2.f * a);
  float m = (1.f - e) / (1.f + e);
  return copysignf(m, v);
}

// ---------------- phase 2: the recurrence, one block per batch element ----
__global__ __launch_bounds__(512, 2) void k_scan(
    const float* __restrict__ times, const float* __restrict__ X,
    const int* __restrict__ fidx,
    const float* __restrict__ w_ih, const float* __restrict__ w_hh,
    const float* __restrict__ b_ih, const float* __restrict__ b_hh,
    const float* __restrict__ lin_w, const float* __restrict__ lin_b,
    const unsigned char* __restrict__ obs, const unsigned* __restrict__ anyv,
    float* __restrict__ out)
{
  const int b = blockIdx.x;
  const int j = threadIdx.x;
  const int fi = fidx[b];
  const float* Xb = X + (size_t)b * T_SZ * C_CH;

  __shared__ float4 h4[HID / 4];        // hidden state
  __shared__ float  g_lds[2 * HID];     // r then z
  __shared__ float  times_lds[T_SZ];
  __shared__ float4 xs4[2][8];          // double-buffered x-piece (ch 33..64)
  __shared__ float  xd0f[2];            // channel-0 value (time channel)
  __shared__ int    flagA[2], flagO[2];

  float* hf = (float*)h4;

  times_lds[j] = times[j];              // blockDim == T_SZ == 512
  if (j < HID) hf[j] = 0.f;

  // weights: thread j owns gate-row j entirely in registers
  float wih[32];
  float whh[HID];
  float bi = 0.f, bh = 0.f;
  const bool act = (j < G3);
  if (act) {
    const float* wi = w_ih + j * 32;
    #pragma unroll
    for (int k = 0; k < 32; ++k) wih[k] = wi[k];
    const float* wh = w_hh + (size_t)j * HID;
    #pragma unroll
    for (int k = 0; k < HID; ++k) whh[k] = wh[k];
    bi = b_ih[j];
    bh = b_hh[j];
  }

  // stage step 0 into parity 0
  if (j < 32)       ((float*)xs4[0])[j] = Xb[33 + j];
  else if (j == 32) xd0f[0] = Xb[0];
  else if (j == 33) flagA[0] = (int)anyv[0];
  else if (j == 34) flagO[0] = (int)obs[(size_t)b * T_SZ];
  float dt = 0.f;
  __syncthreads();

  for (int t = 0; t <= fi; ++t) {
    const int p = t & 1;

    // issue prefetch of step t+1 early (latency hides under the matvec)
    float vnext = 0.f; int fnext = 0;
    const int tn = (t < fi) ? (t + 1) : fi;
    if (j < 32)       vnext = Xb[tn * C_CH + 33 + j];
    else if (j == 32) vnext = Xb[tn * C_CH];
    else if (j == 33) fnext = (int)anyv[tn];
    else if (j == 34) fnext = (int)obs[(size_t)b * T_SZ + tn];

    const int fa = flagA[p];
    const int fo = flagO[p];

    if (fa) {
      if (fo) {
        // ---- full GRU step ----
        float gi = 0.f, gh = 0.f;
        if (act) {
          const float4* xsp = xs4[p];
          float4 xv = xsp[0];
          float xa0 = fmaf(wih[0], xv.x + dt, bi);
          float xa1 = wih[1] * xv.y;
          float xa2 = wih[2] * xv.z;
          float xa3 = wih[3] * xv.w;
          #pragma unroll
          for (int q = 1; q < 8; ++q) {
            float4 v = xsp[q];
            xa0 = fmaf(wih[4 * q + 0], v.x, xa0);
            xa1 = fmaf(wih[4 * q + 1], v.y, xa1);
            xa2 = fmaf(wih[4 * q + 2], v.z, xa2);
            xa3 = fmaf(wih[4 * q + 3], v.w, xa3);
          }
          gi = (xa0 + xa1) + (xa2 + xa3);

          float ha0 = bh, ha1 = 0.f, ha2 = 0.f, ha3 = 0.f;
          #pragma unroll
          for (int q = 0; q < HID / 4; ++q) {
            float4 hv = h4[q];
            ha0 = fmaf(whh[4 * q + 0], hv.x, ha0);
            ha1 = fmaf(whh[4 * q + 1], hv.y, ha1);
            ha2 = fmaf(whh[4 * q + 2], hv.z, ha2);
            ha3 = fmaf(whh[4 * q + 3], hv.w, ha3);
          }
          gh = (ha0 + ha1) + (ha2 + ha3);

          if (j < 2 * HID) g_lds[j] = sigm_f(gi + gh);
        }
        __syncthreads();   // r,z visible; all h reads done
        if (act && j >= 2 * HID) {
          const int k = j - 2 * HID;
          float r = g_lds[k];
          float z = g_lds[HID + k];
          float n = tanh_f(fmaf(r, gh, gi));
          float ho = hf[k];
          hf[k] = fmaf(z, ho - n, n);   // (1-z)*n + z*h
        }
      } else {
        // dt-only step (uniform, redundantly computed by every thread)
        dt += xd0f[p] - times_lds[(t == 0) ? 0 : (t - 1)];
      }
    }
    // common tail: publish prefetched step t+1, then barrier
    if (j < 32)       ((float*)xs4[p ^ 1])[j] = vnext;
    else if (j == 32) xd0f[p ^ 1] = vnext;
    else if (j == 33) flagA[p ^ 1] = fnext;
    else if (j == 34) flagO[p ^ 1] = fnext;
    __syncthreads();
  }

  // final linear: out = lin_w @ h + lin_b
  if (j < OUTD) {
    const float* lw = lin_w + j * HID;
    float acc = lin_b[j];
    #pragma unroll
    for (int k = 0; k < HID; ++k) acc = fmaf(lw[k], hf[k], acc);
    out[(size_t)b * OUTD + j] = acc;
  }
}

extern "C" void kernel_launch(void* const* d_in, const int* in_sizes, int n_in,
                              void* d_out, int out_size, void* d_ws, size_t ws_size,
                              hipStream_t stream) {
  const float* times = (const float*)d_in[0];
  const float* X     = (const float*)d_in[1];
  const int*   fidx  = (const int*)d_in[2];
  const float* w_ih  = (const float*)d_in[3];
  const float* w_hh  = (const float*)d_in[4];
  const float* b_ih  = (const float*)d_in[5];
  const float* b_hh  = (const float*)d_in[6];
  const float* lin_w = (const float*)d_in[7];
  const float* lin_b = (const float*)d_in[8];
  float* outp = (float*)d_out;

  unsigned char* obs = (unsigned char*)d_ws;
  unsigned* anyv = (unsigned*)((char*)d_ws + (size_t)B_SZ * T_SZ);

  k_zero<<<1, 512, 0, stream>>>(anyv);
  k_obs<<<B_SZ, 256, 0, stream>>>(X, obs, anyv);
  k_scan<<<B_SZ, 512, 0, stream>>>(times, X, fidx, w_ih, w_hh, b_ih, b_hh,
                                   lin_w, lin_b, obs, anyv, outp);
}